// Round 9
// baseline (692.941 us; speedup 1.0000x reference)
//
#include <hip/hip_runtime.h>
#include <math.h>

// ---------------------------------------------------------------------------
// GeoSSL PDM loss on MI355X.
// v9: TWO DISPATCHES TOTAL.
//  k_prep: W -> bf16 MFMA B-frag repack (blocks 0..799)
//        + X fp32 -> bf16 padded [G][320] repack Xb (streaming, full HBM BW;
//          mlp then reads HALF the bytes, L3-resident, no convert VALU)
//        + zero accA/accC/ticket (last block)   -> replaces 2 memsets.
//  k_main: graph blocks (quad-per-graph; [s,e) via BINARY SEARCH on sorted
//          n2g -- kills k_bnd + gs/ge buffers) + mlp blocks (TM=32 fused
//          MLP+CE reading Xb), co-resident; LAST-BLOCK TICKET does the final
//          512-double reduce and writes out -- kills k_final.
// Rationale: r8 showed ~190us of per-iteration cost outside the main kernel
// (small kernels + launch gaps), and k_mlp's invariant ~150us == X(120MB) at
// the measured ~800 GB/s stream rate (B-hoist r1 proved the GEMM loop isn't
// the limiter). Halve X bytes + cut dispatches.
// ---------------------------------------------------------------------------

typedef __attribute__((ext_vector_type(8))) short bf16x8; // 8 bf16 (4 VGPRs)
typedef __attribute__((ext_vector_type(4))) short s16x4;
typedef __attribute__((ext_vector_type(4))) float f32x4;

__device__ __forceinline__ short bt(float f) {       // trunc f32->bf16 (1 inst)
    return (short)(__float_as_uint(f) >> 16);
}

#define TM   32    // rows per mlp block
#define DRL  300   // real D
#define DP   320   // padded N and K (10 chunks of 32)
#define XS   328   // X/H LDS row stride in shorts
#define NT   20    // N tiles of 16 (total)
#define NW   5     // N tiles per wave (4 waves x 5 = 20)
#define KCH  10    // K chunks of 32
#define NB_PREPW 800    // 2*DP*DP / 256

// ---------------- k_prep: W repack + X->bf16 repack + zero accs ----------

__global__ __launch_bounds__(256)
void k_prep(const float* __restrict__ W1, const float* __restrict__ W2,
            short* __restrict__ Wb1, short* __restrict__ Wb2,
            const float* __restrict__ X, short* __restrict__ Xb,
            double* __restrict__ accZ, int G, int nxb) {
    const int bid = blockIdx.x;
    const int tid = threadIdx.x;
    if (bid < NB_PREPW) {
        int id = bid * 256 + tid;           // < 2*DP*DP by construction
        int mat = id / (DP * DP);
        int rem = id - mat * DP * DP;
        int k = rem / DP, n = rem - (rem / DP) * DP;
        const float* W = mat ? W2 : W1;
        short* Wb = mat ? Wb2 : Wb1;
        float v = (k < DRL && n < DRL) ? W[k * DRL + n] : 0.f;
        int kc = k >> 5, kin = k & 31, quad = kin >> 3, j = kin & 7;
        int t = n >> 4, l16 = n & 15;
        Wb[(((kc * NT + t) * 64) + quad * 16 + l16) * 8 + j] = bt(v);
    } else if (bid < NB_PREPW + nxb) {
        // X [G][300] fp32 -> Xb [G][320] bf16 (cols 300..319 zero)
        int id = (bid - NB_PREPW) * 256 + tid;     // s16x4 units: G*80
        if (id < G * 80) {
            int row = id / 80, grp = id - (id / 80) * 80;
            float4 v = {0.f, 0.f, 0.f, 0.f};
            if (grp < 75) v = ((const float4*)X)[row * 75 + grp];
            s16x4 sv = { bt(v.x), bt(v.y), bt(v.z), bt(v.w) };
            ((s16x4*)Xb)[row * 80 + grp] = sv;
        }
    } else {
        // zero accA[0..255], accC[256..511], ticket (accZ[512] low word)
        accZ[tid] = 0.0;
        accZ[256 + tid] = 0.0;
        if (tid == 0) ((unsigned int*)&accZ[512])[0] = 0u;
    }
}

// ---------------- k_main: graph + mlp blocks + last-block finalize --------

__global__ __launch_bounds__(256, 4)
void k_main(const int* __restrict__ n2g,
            const float* __restrict__ pt, const float* __restrict__ pp,
            const float* __restrict__ pnp,
            const int* __restrict__ nl, const float* __restrict__ sigmas,
            const float* __restrict__ X, const short* __restrict__ Xb,
            const short* __restrict__ Wb1, const short* __restrict__ Wb2,
            const float* __restrict__ b1, const float* __restrict__ b2,
            double* __restrict__ accA, double* __restrict__ accC,
            unsigned int* __restrict__ ticket, float* __restrict__ out,
            float invG, int G, int N, int nblocks, int useXb) {
    __shared__ __align__(16) short Xs[TM * XS];   // mlp path (20.5 KB)
    __shared__ int lastBlk;
    __shared__ double ax[4], cx[4];

    const int bid = blockIdx.x;
    const int tid = threadIdx.x;
    const int t3  = bid / 3;
    const int r3  = bid - t3 * 3;

    if (r3 == 0) {
        // ================= GRAPH BLOCK (quad per graph) =================
        const int tg = t3 * 256 + tid;
        const int g  = tg >> 2;
        const int j  = tg & 3;
        const int lane = tid & 63;
        float q = 0.f;
        if (g < G) {
            // [s,e) by binary search: lanes j&1==0 -> lb(g), j&1==1 -> lb(g+1)
            int target = g + (j & 1);
            int lo = 0, hi = N;
            while (lo < hi) {
                int mid = (int)(((unsigned)lo + (unsigned)hi) >> 1);
                if (n2g[mid] < target) lo = mid + 1; else hi = mid;
            }
            const int qb = lane & ~3;
            const int s = __shfl(lo, qb + 0, 64);
            const int e = __shfl(lo, qb + 1, 64);
            const int g0 = s >> 2, g1 = (e + 3) >> 2;
            const float4* ptv = (const float4*)pt;
            const float4* ppv = (const float4*)pp;
            const float4* pnv = (const float4*)pnp;
            float st0=0,st1=0,st2=0, sp0=0,sp1=0,sp2=0;
            float m00=0,m01=0,m02=0,m11=0,m12=0,m22=0;
            float t00=0,t01=0,t02=0,t10=0,t11=0,t12=0,t20=0,t21=0,t22=0;
            for (int gg = g0 + j; gg < g1; gg += 4) {
                float4 x0 = ptv[3*gg], x1 = ptv[3*gg+1], x2 = ptv[3*gg+2];
                float4 y0 = ppv[3*gg], y1 = ppv[3*gg+1], y2 = ppv[3*gg+2];
                float A[12] = {x0.x,x0.y,x0.z,x0.w, x1.x,x1.y,x1.z,x1.w,
                               x2.x,x2.y,x2.z,x2.w};
                float B[12] = {y0.x,y0.y,y0.z,y0.w, y1.x,y1.y,y1.z,y1.w,
                               y2.x,y2.y,y2.z,y2.w};
                const int base = gg * 4;
#pragma unroll
                for (int k = 0; k < 4; ++k) {
                    const int i = base + k;
                    const bool v = (i >= s) && (i < e);
                    float a0 = v ? A[3*k+0] : 0.f;
                    float a1 = v ? A[3*k+1] : 0.f;
                    float a2 = v ? A[3*k+2] : 0.f;
                    float b0 = v ? B[3*k+0] : 0.f;
                    float b1v = v ? B[3*k+1] : 0.f;
                    float b2v = v ? B[3*k+2] : 0.f;
                    st0 += a0; st1 += a1; st2 += a2;
                    sp0 += b0; sp1 += b1v; sp2 += b2v;
                    m00 += b0*b0;  m01 += b0*b1v;  m02 += b0*b2v;
                    m11 += b1v*b1v; m12 += b1v*b2v; m22 += b2v*b2v;
                    t00 += a0*b0; t01 += a0*b1v; t02 += a0*b2v;
                    t10 += a1*b0; t11 += a1*b1v; t12 += a1*b2v;
                    t20 += a2*b0; t21 += a2*b1v; t22 += a2*b2v;
                }
            }
#define QR(x) do { x += __shfl_xor(x, 1, 64); x += __shfl_xor(x, 2, 64); } while (0)
            QR(st0); QR(st1); QR(st2); QR(sp0); QR(sp1); QR(sp2);
            QR(m00); QR(m01); QR(m02); QR(m11); QR(m12); QR(m22);
            QR(t00); QR(t01); QR(t02); QR(t10); QR(t11); QR(t12);
            QR(t20); QR(t21); QR(t22);
#undef QR
            float cnt = fmaxf((float)(e - s), 1.f);
            float ic  = 1.f / cnt;
            float c0 = st0 * ic, c1 = st1 * ic, c2 = st2 * ic;
            float d0 = sp0 * ic, d1 = sp1 * ic, d2 = sp2 * ic;
            float p00 = m00 - cnt*d0*d0, p01 = m01 - cnt*d0*d1;
            float p02 = m02 - cnt*d0*d2, p11 = m11 - cnt*d1*d1;
            float p12 = m12 - cnt*d1*d2, p22 = m22 - cnt*d2*d2;
            float o00 = t00 - cnt*c0*d0, o01 = t01 - cnt*c0*d1, o02 = t02 - cnt*c0*d2;
            float o10 = t10 - cnt*c1*d0, o11 = t11 - cnt*c1*d1, o12 = t12 - cnt*c1*d2;
            float o20 = t20 - cnt*c2*d0, o21 = t21 - cnt*c2*d1, o22 = t22 - cnt*c2*d2;
            float ptn = sqrtf(p00*p00 + p11*p11 + p22*p22 +
                              2.f*(p01*p01 + p02*p02 + p12*p12));
            float otn = sqrtf(o00*o00 + o01*o01 + o02*o02 +
                              o10*o10 + o11*o11 + o12*o12 +
                              o20*o20 + o21*o21 + o22*o22);
            float den = ptn + otn;
            float idn = (den > 0.f) ? (1.f / den) : 0.f;
            float sg  = sigmas[nl[g]];
            float is2 = 1.f / (sg * sg);
            for (int gg = g0 + j; gg < g1; gg += 4) {
                float4 x0 = ptv[3*gg], x1 = ptv[3*gg+1], x2 = ptv[3*gg+2];
                float4 y0 = ppv[3*gg], y1 = ppv[3*gg+1], y2 = ppv[3*gg+2];
                float4 z0 = pnv[3*gg], z1 = pnv[3*gg+1], z2 = pnv[3*gg+2];
                float A[12] = {x0.x,x0.y,x0.z,x0.w, x1.x,x1.y,x1.z,x1.w,
                               x2.x,x2.y,x2.z,x2.w};
                float B[12] = {y0.x,y0.y,y0.z,y0.w, y1.x,y1.y,y1.z,y1.w,
                               y2.x,y2.y,y2.z,y2.w};
                float C[12] = {z0.x,z0.y,z0.z,z0.w, z1.x,z1.y,z1.z,z1.w,
                               z2.x,z2.y,z2.z,z2.w};
                const int base = gg * 4;
#pragma unroll
                for (int k = 0; k < 4; ++k) {
                    const int i = base + k;
                    const bool v = (i >= s) && (i < e);
                    float a0 = A[3*k+0] - c0, a1 = A[3*k+1] - c1, a2 = A[3*k+2] - c2;
                    float bb0 = B[3*k+0], bb1 = B[3*k+1], bb2 = B[3*k+2];
                    float b0 = bb0 - d0, b1v = bb1 - d1, b2v = bb2 - d2;
                    float n0 = -2.f * ((b0*p00 + b1v*p01 + b2v*p02) - (a0*o00 + a1*o10 + a2*o20));
                    float n1 = -2.f * ((b0*p01 + b1v*p11 + b2v*p12) - (a0*o01 + a1*o11 + a2*o21));
                    float n2 = -2.f * ((b0*p02 + b1v*p12 + b2v*p22) - (a0*o02 + a1*o12 + a2*o22));
                    float e0 = (C[3*k+0] - bb0) - n0 * idn;
                    float e1 = (C[3*k+1] - bb1) - n1 * idn;
                    float e2 = (C[3*k+2] - bb2) - n2 * idn;
                    float contrib = (e0*e0 + e1*e1 + e2*e2) * is2;
                    q += v ? contrib : 0.f;
                }
            }
        }
        for (int o = 32; o > 0; o >>= 1) q += __shfl_down(q, o, 64);
        if ((tid & 63) == 0) {
            atomicAdd(&accA[(t3 * 4 + (tid >> 6)) & 255], (double)q);
            __threadfence();
        }
    } else {
        // ==================== MLP BLOCK (TM=32, 4 waves) ====================
        const int mid = t3 * 2 + (r3 - 1);    // may reach 3126; self-guarded
        const int wv   = tid >> 6;
        const int lane = tid & 63;
        const int quad = lane >> 4;
        const int l16  = lane & 15;
        const int m0   = mid * TM;
        const int tb0  = wv * NW;

        if (useXb) {
            // stage from pre-converted bf16 Xb[G][320]: 5 x 16B per thread
            const bf16x8* Xbv = (const bf16x8*)Xb;   // row = 40 units
#pragma unroll
            for (int u = 0; u < 5; ++u) {
                int idx = tid + u * 256;             // 0..1279 = 32*40
                int r = idx / 40, c8 = idx - (idx / 40) * 40;
                int gr = m0 + r;
                bf16x8 v = (bf16x8){0,0,0,0,0,0,0,0};
                if (gr < G) v = Xbv[gr * 40 + c8];
                *(bf16x8*)&Xs[r * XS + c8 * 8] = v;
            }
        } else {
            // fallback: stage from fp32 X with convert
            const float4* Xv = (const float4*)X;
            for (int idx = tid; idx < TM * 75; idx += 256) {
                int r = idx / 75, c = idx - r * 75;
                int gr = m0 + r;
                float4 v = {0.f, 0.f, 0.f, 0.f};
                if (gr < G) v = Xv[gr * 75 + c];
                s16x4 sv = { bt(v.x), bt(v.y), bt(v.z), bt(v.w) };
                *(s16x4*)&Xs[r * XS + c * 4] = sv;
            }
            for (int idx = tid; idx < TM * (DP - DRL); idx += 256) {
                int r = idx / (DP - DRL), c = idx - r * (DP - DRL);
                Xs[r * XS + DRL + c] = 0;
            }
        }
        __syncthreads();

        const bf16x8* B1 = (const bf16x8*)Wb1;
        const bf16x8* B2 = (const bf16x8*)Wb2;

        f32x4 acc[2][NW];
        const f32x4 vzero = {0.f, 0.f, 0.f, 0.f};
#pragma unroll
        for (int m = 0; m < 2; ++m)
#pragma unroll
            for (int n = 0; n < NW; ++n) acc[m][n] = vzero;

        // ---- GEMM1 ----
#pragma unroll
        for (int kc = 0; kc < KCH; ++kc) {
            bf16x8 bv[NW];
#pragma unroll
            for (int n = 0; n < NW; ++n) bv[n] = B1[(kc * NT + tb0 + n) * 64 + lane];
            bf16x8 a0 = *(const bf16x8*)&Xs[(l16) * XS + kc * 32 + quad * 8];
            bf16x8 a1 = *(const bf16x8*)&Xs[(16 + l16) * XS + kc * 32 + quad * 8];
#pragma unroll
            for (int n = 0; n < NW; ++n) {
                acc[0][n] = __builtin_amdgcn_mfma_f32_16x16x32_bf16(a0, bv[n], acc[0][n], 0, 0, 0);
                acc[1][n] = __builtin_amdgcn_mfma_f32_16x16x32_bf16(a1, bv[n], acc[1][n], 0, 0, 0);
            }
        }
        __syncthreads();

        // silu epilogue -> H in place
#pragma unroll
        for (int n = 0; n < NW; ++n) {
            int col = (tb0 + n) * 16 + l16;
            float bias = (col < DRL) ? b1[col] : 0.f;
#pragma unroll
            for (int m = 0; m < 2; ++m)
#pragma unroll
                for (int r = 0; r < 4; ++r) {
                    float v = acc[m][n][r] + bias;
                    float h = v / (1.f + __expf(-v));
                    Xs[(m * 16 + quad * 4 + r) * XS + col] = bt(h);
                }
        }
        __syncthreads();

        // ---- GEMM2 ----
#pragma unroll
        for (int m = 0; m < 2; ++m)
#pragma unroll
            for (int n = 0; n < NW; ++n) acc[m][n] = vzero;
#pragma unroll
        for (int kc = 0; kc < KCH; ++kc) {
            bf16x8 bv[NW];
#pragma unroll
            for (int n = 0; n < NW; ++n) bv[n] = B2[(kc * NT + tb0 + n) * 64 + lane];
            bf16x8 a0 = *(const bf16x8*)&Xs[(l16) * XS + kc * 32 + quad * 8];
            bf16x8 a1 = *(const bf16x8*)&Xs[(16 + l16) * XS + kc * 32 + quad * 8];
#pragma unroll
            for (int n = 0; n < NW; ++n) {
                acc[0][n] = __builtin_amdgcn_mfma_f32_16x16x32_bf16(a0, bv[n], acc[0][n], 0, 0, 0);
                acc[1][n] = __builtin_amdgcn_mfma_f32_16x16x32_bf16(a1, bv[n], acc[1][n], 0, 0, 0);
            }
        }
        __syncthreads();   // Xs becomes CE scratch

        // ---- CE ----
        float* S = (float*)Xs;
        float* T = S + TM * 4;
#pragma unroll
        for (int m = 0; m < 2; ++m) {
#pragma unroll
            for (int r = 0; r < 4; ++r) {
                int row = m * 16 + quad * 4 + r;
                int grow = m0 + row;
                int ct = (grow < G) ? nl[grow] : -1;
                float sw = 0.f;
#pragma unroll
                for (int n = 0; n < NW; ++n) {
                    int col = (tb0 + n) * 16 + l16;
                    float lg = acc[m][n][r] + ((col < DRL) ? b2[col] : 0.f);
                    if (col < DRL) sw += __expf(lg);
                    if (col == ct) T[row] = lg;
                }
                for (int o = 1; o < 16; o <<= 1) sw += __shfl_xor(sw, o, 64);
                if (l16 == 0) S[row * 4 + wv] = sw;
            }
        }
        __syncthreads();
        if (tid < 64) {
            float q = 0.f;
            int row = tid;
            if (row < TM) {
                int grow = m0 + row;
                if (grow < G) {
                    float ss = S[row*4+0] + S[row*4+1] + S[row*4+2] + S[row*4+3];
                    q = __logf(ss) - T[row];
                }
            }
            for (int o = 32; o > 0; o >>= 1) q += __shfl_down(q, o, 64);
            if (tid == 0) {
                atomicAdd(&accC[mid & 255], (double)q);
                __threadfence();
            }
        }
    }

    // ---------------- common tail: last-block finalize --------------------
    __syncthreads();
    if (tid == 0) {
        unsigned int old = atomicAdd(ticket, 1u);
        lastBlk = (old == (unsigned int)(nblocks - 1)) ? 1 : 0;
    }
    __syncthreads();
    if (lastBlk) {
        double a = atomicAdd(&accA[tid], 0.0);   // atomic read: coherent view
        double c = atomicAdd(&accC[tid], 0.0);
        for (int o = 32; o > 0; o >>= 1) {
            a += __shfl_down(a, o, 64);
            c += __shfl_down(c, o, 64);
        }
        if ((tid & 63) == 0) { ax[tid >> 6] = a; cx[tid >> 6] = c; }
        __syncthreads();
        if (tid == 0) {
            double A2 = ax[0] + ax[1] + ax[2] + ax[3];
            double C2 = cx[0] + cx[1] + cx[2] + cx[3];
            out[0] = (float)(A2 * (double)invG);
            out[1] = (float)(C2 * (double)invG);
        }
    }
}

// ---------------- launch -------------------------------------------------

extern "C" void kernel_launch(void* const* d_in, const int* in_sizes, int n_in,
                              void* d_out, int out_size, void* d_ws, size_t ws_size,
                              hipStream_t stream) {
    const int*   n2g = (const int*)d_in[0];
    const int*   nl  = (const int*)d_in[2];
    const float* X   = (const float*)d_in[4];   // molecule_repr [G,300]
    const float* pnp = (const float*)d_in[5];   // pos_noise_pred [N,3]
    const float* pp  = (const float*)d_in[6];   // pos_perturbed  [N,3]
    const float* pt  = (const float*)d_in[7];   // pos_target     [N,3]
    const float* W1  = (const float*)d_in[8];
    const float* b1  = (const float*)d_in[9];
    const float* W2  = (const float*)d_in[10];
    const float* b2  = (const float*)d_in[11];
    const float* sig = (const float*)d_in[12];

    const int N = in_sizes[0];
    const int G = in_sizes[2];

    // workspace: accA[256] | accC[256] | ticket | (pad to 8K) | Wb1 | Wb2 | Xb
    double*       accA   = (double*)d_ws;
    double*       accC   = accA + 256;
    unsigned int* ticket = (unsigned int*)(accA + 512);
    short*        Wb1    = (short*)((char*)d_ws + 8192);
    short*        Wb2    = Wb1 + DP * DP;
    short*        Xb     = Wb2 + DP * DP;      // byte offset 8192+409600
    const size_t need = 8192 + (size_t)2 * DP * DP * 2 + (size_t)G * DP * 2;
    const int useXb = (ws_size >= need) ? 1 : 0;
    const int nxb = useXb ? (G * 80 + 255) / 256 : 0;

    const int nbg   = (4 * G + 255) / 256;    // 1563 graph blocks
    const int nmain = 3 * nbg;                // graph + 2*mlp interleaved

    k_prep<<<NB_PREPW + nxb + 1, 256, 0, stream>>>(W1, W2, Wb1, Wb2,
                                                   X, Xb, accA, G, nxb);
    k_main<<<nmain, 256, 0, stream>>>(n2g, pt, pp, pnp, nl, sig, X, Xb,
                                      Wb1, Wb2, b1, b2, accA, accC, ticket,
                                      (float*)d_out, 1.0f / (float)G,
                                      G, N, nmain, useXb);
}